// Round 8
// baseline (483.293 us; speedup 1.0000x reference)
//
#include <hip/hip_runtime.h>

#define NODE_DIM 128
#define NUM_IRREPS 224
#define SPH_DIM 480
#define HIDDEN 576   // NODE_DIM + 2*NUM_IRREPS
#define NUM_BASIS 20
#define N_NODES 10000
#define N_EDGES 160000
#define NPB 8        // nodes per block in node MLP
#define EB 64        // edges per window (block)
#define CH 16        // edges per chunk

// ---------------- init: d_out = concat(x_scalar, x_spherical); zero counts ----------------
__global__ void init_out(const float* __restrict__ xs,
                         const float* __restrict__ xsp,
                         float* __restrict__ out,
                         int* __restrict__ counts) {
    const int stride = gridDim.x * blockDim.x;
    const int t0 = blockIdx.x * blockDim.x + threadIdx.x;
    for (int i = t0; i < N_NODES * NODE_DIM; i += stride) out[i] = xs[i];
    float* o2 = out + (size_t)N_NODES * NODE_DIM;
    for (int i = t0; i < N_NODES * SPH_DIM; i += stride) o2[i] = xsp[i];
    for (int i = t0; i < N_NODES; i += stride) counts[i] = 0;
}

// ---------------- node MLP: scalar_out = silu(x@W1+b1)@W2+b2 ----------------
__global__ __launch_bounds__(128) void node_mlp(
    const float* __restrict__ x,
    const float* __restrict__ W1, const float* __restrict__ b1,
    const float* __restrict__ W2, const float* __restrict__ b2,
    float* __restrict__ so) {
    __shared__ float xs[NPB][NODE_DIM];
    __shared__ float hs[NPB][NODE_DIM];
    const int tid = threadIdx.x;
    const int n0 = blockIdx.x * NPB;

    #pragma unroll
    for (int n = 0; n < NPB; ++n) {
        int node = n0 + n;
        xs[n][tid] = (node < N_NODES) ? x[(size_t)node * NODE_DIM + tid] : 0.f;
    }
    __syncthreads();

    float acc[NPB];
    #pragma unroll
    for (int n = 0; n < NPB; ++n) acc[n] = b1[tid];
    for (int k = 0; k < NODE_DIM; ++k) {
        float w = W1[k * NODE_DIM + tid];
        #pragma unroll
        for (int n = 0; n < NPB; ++n) acc[n] = fmaf(xs[n][k], w, acc[n]);
    }
    #pragma unroll
    for (int n = 0; n < NPB; ++n) {
        float v = acc[n];
        hs[n][tid] = v / (1.f + __expf(-v));
    }
    __syncthreads();

    for (int j = tid; j < HIDDEN; j += 128) {
        float a2[NPB];
        #pragma unroll
        for (int n = 0; n < NPB; ++n) a2[n] = b2[j];
        for (int k = 0; k < NODE_DIM; ++k) {
            float w = W2[k * HIDDEN + j];
            #pragma unroll
            for (int n = 0; n < NPB; ++n) a2[n] = fmaf(hs[n][k], w, a2[n]);
        }
        #pragma unroll
        for (int n = 0; n < NPB; ++n) {
            int node = n0 + n;
            if (node < N_NODES) so[(size_t)node * HIDDEN + j] = a2[n];
        }
    }
}

// ---------------- CSR build: histogram / scan / scatter ----------------
__global__ __launch_bounds__(256) void hist_kernel(const int* __restrict__ eidx,
                                                   int* __restrict__ counts) {
    int i = blockIdx.x * blockDim.x + threadIdx.x;
    if (i < N_EDGES) atomicAdd(&counts[eidx[i]], 1);   // bucket by src
}

__global__ __launch_bounds__(1024) void scan_kernel(const int* __restrict__ counts,
                                                    int* __restrict__ offsets,
                                                    int* __restrict__ cursor) {
    __shared__ int wsum[16];
    const int tid = threadIdx.x;
    int vals[10];
    int run = 0;
    #pragma unroll
    for (int i = 0; i < 10; ++i) {
        int idx = tid * 10 + i;
        int c = (idx < N_NODES) ? counts[idx] : 0;
        vals[i] = run;
        run += c;
    }
    const int lane = tid & 63, w = tid >> 6;
    int inc = run;
    #pragma unroll
    for (int off = 1; off < 64; off <<= 1) {
        int v = __shfl_up(inc, off);
        if (lane >= off) inc += v;
    }
    if (lane == 63) wsum[w] = inc;
    __syncthreads();
    if (w == 0) {
        int v = (lane < 16) ? wsum[lane] : 0;
        #pragma unroll
        for (int off = 1; off < 16; off <<= 1) {
            int u = __shfl_up(v, off);
            if (lane >= off) v += u;
        }
        if (lane < 16) wsum[lane] = v;
    }
    __syncthreads();
    const int wbase = (w > 0) ? wsum[w - 1] : 0;
    const int base = wbase + inc - run;   // exclusive prefix
    #pragma unroll
    for (int i = 0; i < 10; ++i) {
        int idx = tid * 10 + i;
        if (idx < N_NODES) {
            int v = base + vals[i];
            offsets[idx] = v;
            cursor[idx] = v;
        }
    }
    if (tid == 1023) offsets[N_NODES] = wbase + inc;
}

__global__ __launch_bounds__(256) void scatter_kernel(const int* __restrict__ eidx,
                                                      int* __restrict__ cursor,
                                                      int* __restrict__ edge_order,
                                                      int* __restrict__ edge_src) {
    int i = blockIdx.x * blockDim.x + threadIdx.x;
    if (i < N_EDGES) {
        int s = eidx[i];
        int pos = atomicAdd(&cursor[s], 1);
        edge_order[pos] = i;
        edge_src[pos] = s;
    }
}

// ---------------- edge window kernel: 64 sorted edges/block, segmented reduce ----------------
// Phase A (per 16-edge chunk): thread t computes filter cols {t, 256+t, 512+t(t<64)}
//   for all 16 edges -> fo_s[16][HIDDEN] in LDS (fo = (rbf@Wr+br)*fcut*so[dst]).
// Phase B: thread t owns outputs: sph d=t, d=256+t (t<224), scalar t (t<128);
//   coalesced xsp/rsh loads; accumulate until src changes (block-uniform), then
//   flush via atomicAdd. All edges in a window are independent -> deep ILP.
__global__ __launch_bounds__(256, 1) void edge_win(
    const float* __restrict__ xsp,
    const float* __restrict__ rbf, const float* __restrict__ fcut,
    const float* __restrict__ rsh, const int* __restrict__ eidx,
    const float* __restrict__ Wr, const float* __restrict__ br,
    const float* __restrict__ so,
    const int* __restrict__ edge_order, const int* __restrict__ edge_src,
    float* __restrict__ out_scalar, float* __restrict__ out_sph)
{
    __shared__ float rbf_s[EB][NUM_BASIS];       // 5 KB (row = 80 B, 16B-aligned)
    __shared__ float fo_s[CH][HIDDEN + 8];       // 36.5 KB
    __shared__ int   e_s[EB];
    __shared__ int   src_s[EB];
    __shared__ int   dst_s[EB];
    __shared__ float fc_s[EB];

    const int t = threadIdx.x;
    const int base = blockIdx.x * EB;

    const bool has3 = (t < 64);
    const int c_a = t, c_b = 256 + t, c_c = 512 + t;

    // Wr columns in registers (launch_bounds(...,1) -> allocator may keep them)
    float wA[NUM_BASIS], wB[NUM_BASIS], wC[NUM_BASIS];
    #pragma unroll
    for (int k = 0; k < NUM_BASIS; ++k) {
        wA[k] = Wr[k * HIDDEN + c_a];
        wB[k] = Wr[k * HIDDEN + c_b];
        wC[k] = has3 ? Wr[k * HIDDEN + c_c] : 0.f;
    }
    const float bA = br[c_a], bB = br[c_b], bC = has3 ? br[c_c] : 0.f;

    if (t < EB) {
        int pos = base + t;
        int e = edge_order[pos];
        e_s[t]   = e;
        src_s[t] = edge_src[pos];
        dst_s[t] = eidx[N_EDGES + e];
        fc_s[t]  = fcut[e];
    }
    __syncthreads();
    // stage rbf rows (coalesced within each 20-float row)
    for (int i = t; i < EB * NUM_BASIS; i += 256) {
        int le = i / NUM_BASIS, k = i - le * NUM_BASIS;
        rbf_s[le][k] = rbf[(size_t)e_s[le] * NUM_BASIS + k];
    }

    // phase-B gate indices for owned sph elements d1=t, d2=256+t
    const int g1i = (t < 128) ? t : (128 + (t - 128) / 3);
    const int g2i = (t < 64) ? (128 + (128 + t) / 3) : (192 + (t - 64) / 5);

    float accS = 0.f, accD1 = 0.f, accD2 = 0.f;
    __syncthreads();
    int cur_src = src_s[0];

    for (int c = 0; c < EB / CH; ++c) {
        // ---- phase A: filter values for CH edges ----
        for (int le = 0; le < CH; ++le) {
            const int e = c * CH + le;
            const int dst = dst_s[e];
            const float fc = fc_s[e];
            const float* sod = so + (size_t)dst * HIDDEN;
            const float4* rq = (const float4*)rbf_s[e];
            float4 q0 = rq[0], q1 = rq[1], q2 = rq[2], q3 = rq[3], q4 = rq[4];
            float a0 = bA, a1 = bB, a2 = bC;
            const float rb[NUM_BASIS] = {q0.x,q0.y,q0.z,q0.w, q1.x,q1.y,q1.z,q1.w,
                                         q2.x,q2.y,q2.z,q2.w, q3.x,q3.y,q3.z,q3.w,
                                         q4.x,q4.y,q4.z,q4.w};
            #pragma unroll
            for (int k = 0; k < NUM_BASIS; ++k) {
                a0 = fmaf(rb[k], wA[k], a0);
                a1 = fmaf(rb[k], wB[k], a1);
                a2 = fmaf(rb[k], wC[k], a2);
            }
            fo_s[le][c_a] = a0 * fc * sod[c_a];
            fo_s[le][c_b] = a1 * fc * sod[c_b];
            if (has3) fo_s[le][c_c] = a2 * fc * sod[c_c];
        }
        __syncthreads();
        // ---- phase B: consume, segmented accumulate ----
        for (int le = 0; le < CH; ++le) {
            const int e = c * CH + le;
            const int s = src_s[e];
            if (s != cur_src) {   // block-uniform branch
                atomicAdd(&out_sph[(size_t)cur_src * SPH_DIM + t], accD1);
                if (t < 224) atomicAdd(&out_sph[(size_t)cur_src * SPH_DIM + 256 + t], accD2);
                if (t < 128) atomicAdd(&out_scalar[(size_t)cur_src * NODE_DIM + t], accS);
                accD1 = accD2 = accS = 0.f;
                cur_src = s;
            }
            const int dst = dst_s[e];
            const int eg  = e_s[e];
            const float xv1 = xsp[(size_t)dst * SPH_DIM + t];
            const float rv1 = rsh[(size_t)eg  * SPH_DIM + t];
            accD1 = fmaf(xv1, fo_s[le][g1i], fmaf(rv1, fo_s[le][NUM_IRREPS + g1i], accD1));
            if (t < 224) {
                const float xv2 = xsp[(size_t)dst * SPH_DIM + 256 + t];
                const float rv2 = rsh[(size_t)eg  * SPH_DIM + 256 + t];
                accD2 = fmaf(xv2, fo_s[le][g2i], fmaf(rv2, fo_s[le][NUM_IRREPS + g2i], accD2));
            }
            if (t < 128) accS += fo_s[le][2 * NUM_IRREPS + t];
        }
        __syncthreads();
    }
    // final flush
    atomicAdd(&out_sph[(size_t)cur_src * SPH_DIM + t], accD1);
    if (t < 224) atomicAdd(&out_sph[(size_t)cur_src * SPH_DIM + 256 + t], accD2);
    if (t < 128) atomicAdd(&out_scalar[(size_t)cur_src * NODE_DIM + t], accS);
}

extern "C" void kernel_launch(void* const* d_in, const int* in_sizes, int n_in,
                              void* d_out, int out_size, void* d_ws, size_t ws_size,
                              hipStream_t stream) {
    const float* x_scalar    = (const float*)d_in[0];
    const float* x_spherical = (const float*)d_in[1];
    const float* rbf         = (const float*)d_in[2];
    const float* fcut        = (const float*)d_in[3];
    const float* rsh         = (const float*)d_in[4];
    const int*   eidx        = (const int*)d_in[5];
    const float* W1          = (const float*)d_in[6];
    const float* b1          = (const float*)d_in[7];
    const float* W2          = (const float*)d_in[8];
    const float* b2          = (const float*)d_in[9];
    const float* Wr          = (const float*)d_in[10];
    const float* br          = (const float*)d_in[11];

    float* out        = (float*)d_out;
    float* out_scalar = out;                                   // (N_NODES, 128)
    float* out_sph    = out + (size_t)N_NODES * NODE_DIM;      // (N_NODES, 480)

    // workspace layout
    float* scalar_out = (float*)d_ws;                          // 10000*576 floats
    int*   counts     = (int*)(scalar_out + (size_t)N_NODES * HIDDEN);   // 10000
    int*   offsets    = counts + N_NODES;                      // 10001
    int*   cursor     = offsets + N_NODES + 1;                 // 10000
    int*   edge_order = cursor + N_NODES;                      // 160000
    int*   edge_src   = edge_order + N_EDGES;                  // 160000

    init_out<<<2048, 256, 0, stream>>>(x_scalar, x_spherical, out, counts);
    hist_kernel<<<(N_EDGES + 255) / 256, 256, 0, stream>>>(eidx, counts);
    scan_kernel<<<1, 1024, 0, stream>>>(counts, offsets, cursor);
    scatter_kernel<<<(N_EDGES + 255) / 256, 256, 0, stream>>>(eidx, cursor, edge_order, edge_src);
    node_mlp<<<(N_NODES + NPB - 1) / NPB, 128, 0, stream>>>(x_scalar, W1, b1, W2, b2, scalar_out);
    edge_win<<<N_EDGES / EB, 256, 0, stream>>>(x_spherical, rbf, fcut, rsh, eidx,
                                               Wr, br, scalar_out, edge_order, edge_src,
                                               out_scalar, out_sph);
}

// Round 9
// 357.172 us; speedup vs baseline: 1.3531x; 1.3531x over previous
//
#include <hip/hip_runtime.h>

#define NODE_DIM 128
#define NUM_IRREPS 224
#define SPH_DIM 480
#define HIDDEN 576   // NODE_DIM + 2*NUM_IRREPS
#define NUM_BASIS 20
#define N_NODES 10000
#define N_EDGES 160000
#define NPB 8        // nodes per block in node MLP
#define EB 32        // edges per window (block)
#define NT 36        // N-tiles (576/16)

typedef __attribute__((ext_vector_type(8))) short short8v;   // 8 bf16
typedef __attribute__((ext_vector_type(4))) float f32x4;

__device__ __forceinline__ unsigned short f2bf(float f) {
    unsigned int u = __builtin_bit_cast(unsigned int, f);
    u = (u + 0x7fff + ((u >> 16) & 1)) >> 16;   // RNE
    return (unsigned short)u;
}
__device__ __forceinline__ float bf2f(unsigned short h) {
    unsigned int u = ((unsigned int)h) << 16;
    return __builtin_bit_cast(float, u);
}

// ---------------- init: d_out = concat(x_scalar, x_spherical); zero counts ----------------
__global__ void init_out(const float* __restrict__ xs,
                         const float* __restrict__ xsp,
                         float* __restrict__ out,
                         int* __restrict__ counts) {
    const int stride = gridDim.x * blockDim.x;
    const int t0 = blockIdx.x * blockDim.x + threadIdx.x;
    for (int i = t0; i < N_NODES * NODE_DIM; i += stride) out[i] = xs[i];
    float* o2 = out + (size_t)N_NODES * NODE_DIM;
    for (int i = t0; i < N_NODES * SPH_DIM; i += stride) o2[i] = xsp[i];
    for (int i = t0; i < N_NODES; i += stride) counts[i] = 0;
}

// ---------------- Wr -> MFMA B-fragments (bf16, K padded 20->32) ----------------
// B-frag for 16x16x32: lane l holds col (l&15), k = (l>>4)*8 + j, j=0..7
__global__ void bfrag_prep(const float* __restrict__ Wr, unsigned short* __restrict__ bfrag) {
    const int t = threadIdx.x;
    for (int idx = t; idx < NT * 64; idx += 256) {
        const int nt = idx >> 6, l = idx & 63;
        const int col = nt * 16 + (l & 15);
        const int kb = (l >> 4) * 8;
        #pragma unroll
        for (int j = 0; j < 8; ++j) {
            const int k = kb + j;
            bfrag[(size_t)idx * 8 + j] = (k < NUM_BASIS) ? f2bf(Wr[k * HIDDEN + col]) : (unsigned short)0;
        }
    }
}

// ---------------- node MLP: scalar_out = silu(x@W1+b1)@W2+b2 ----------------
__global__ __launch_bounds__(128) void node_mlp(
    const float* __restrict__ x,
    const float* __restrict__ W1, const float* __restrict__ b1,
    const float* __restrict__ W2, const float* __restrict__ b2,
    float* __restrict__ so) {
    __shared__ float xs[NPB][NODE_DIM];
    __shared__ float hs[NPB][NODE_DIM];
    const int tid = threadIdx.x;
    const int n0 = blockIdx.x * NPB;

    #pragma unroll
    for (int n = 0; n < NPB; ++n) {
        int node = n0 + n;
        xs[n][tid] = (node < N_NODES) ? x[(size_t)node * NODE_DIM + tid] : 0.f;
    }
    __syncthreads();

    float acc[NPB];
    #pragma unroll
    for (int n = 0; n < NPB; ++n) acc[n] = b1[tid];
    for (int k = 0; k < NODE_DIM; ++k) {
        float w = W1[k * NODE_DIM + tid];
        #pragma unroll
        for (int n = 0; n < NPB; ++n) acc[n] = fmaf(xs[n][k], w, acc[n]);
    }
    #pragma unroll
    for (int n = 0; n < NPB; ++n) {
        float v = acc[n];
        hs[n][tid] = v / (1.f + __expf(-v));
    }
    __syncthreads();

    for (int j = tid; j < HIDDEN; j += 128) {
        float a2[NPB];
        #pragma unroll
        for (int n = 0; n < NPB; ++n) a2[n] = b2[j];
        for (int k = 0; k < NODE_DIM; ++k) {
            float w = W2[k * HIDDEN + j];
            #pragma unroll
            for (int n = 0; n < NPB; ++n) a2[n] = fmaf(hs[n][k], w, a2[n]);
        }
        #pragma unroll
        for (int n = 0; n < NPB; ++n) {
            int node = n0 + n;
            if (node < N_NODES) so[(size_t)node * HIDDEN + j] = a2[n];
        }
    }
}

// ---------------- CSR build: histogram / scan / scatter ----------------
__global__ __launch_bounds__(256) void hist_kernel(const int* __restrict__ eidx,
                                                   int* __restrict__ counts) {
    int i = blockIdx.x * blockDim.x + threadIdx.x;
    if (i < N_EDGES) atomicAdd(&counts[eidx[i]], 1);   // bucket by src
}

__global__ __launch_bounds__(1024) void scan_kernel(const int* __restrict__ counts,
                                                    int* __restrict__ offsets,
                                                    int* __restrict__ cursor) {
    __shared__ int wsum[16];
    const int tid = threadIdx.x;
    int vals[10];
    int run = 0;
    #pragma unroll
    for (int i = 0; i < 10; ++i) {
        int idx = tid * 10 + i;
        int c = (idx < N_NODES) ? counts[idx] : 0;
        vals[i] = run;
        run += c;
    }
    const int lane = tid & 63, w = tid >> 6;
    int inc = run;
    #pragma unroll
    for (int off = 1; off < 64; off <<= 1) {
        int v = __shfl_up(inc, off);
        if (lane >= off) inc += v;
    }
    if (lane == 63) wsum[w] = inc;
    __syncthreads();
    if (w == 0) {
        int v = (lane < 16) ? wsum[lane] : 0;
        #pragma unroll
        for (int off = 1; off < 16; off <<= 1) {
            int u = __shfl_up(v, off);
            if (lane >= off) v += u;
        }
        if (lane < 16) wsum[lane] = v;
    }
    __syncthreads();
    const int wbase = (w > 0) ? wsum[w - 1] : 0;
    const int base = wbase + inc - run;   // exclusive prefix
    #pragma unroll
    for (int i = 0; i < 10; ++i) {
        int idx = tid * 10 + i;
        if (idx < N_NODES) {
            int v = base + vals[i];
            offsets[idx] = v;
            cursor[idx] = v;
        }
    }
    if (tid == 1023) offsets[N_NODES] = wbase + inc;
}

__global__ __launch_bounds__(256) void scatter_kernel(const int* __restrict__ eidx,
                                                      int* __restrict__ cursor,
                                                      int* __restrict__ edge_order,
                                                      int* __restrict__ edge_src) {
    int i = blockIdx.x * blockDim.x + threadIdx.x;
    if (i < N_EDGES) {
        int s = eidx[i];
        int pos = atomicAdd(&cursor[s], 1);
        edge_order[pos] = i;
        edge_src[pos] = s;
    }
}

// ---------------- edge MFMA kernel: 32 sorted edges/block ----------------
// Phase A: filter GEMM on matrix cores. A = rbf (32x32 bf16, K pad), B = Wr frags
//   (from ws). Epilogue: fo = (acc + br) * fcut * so[dst] -> bf16 LDS [32][584].
// Phase B: thread t owns sph d=t, d=256+t (t<224), scalar t (t<128); coalesced
//   xsp/rsh; segmented accumulate, atomicAdd flush on (block-uniform) src change.
__global__ __launch_bounds__(256) void edge_mfma(
    const float* __restrict__ xsp,
    const float* __restrict__ rbf, const float* __restrict__ fcut,
    const float* __restrict__ rsh, const int* __restrict__ eidx,
    const unsigned short* __restrict__ bfrag, const float* __restrict__ br,
    const float* __restrict__ so,
    const int* __restrict__ edge_order, const int* __restrict__ edge_src,
    float* __restrict__ out_scalar, float* __restrict__ out_sph)
{
    __shared__ unsigned short rbfA[2][64][8];     // A-frags, 2 M-tiles   (2 KB)
    __shared__ unsigned short fo_bf[EB][HIDDEN + 8];  // filter_out bf16 (37.4 KB)
    __shared__ int   e_s[EB];
    __shared__ int   src_s[EB];
    __shared__ int   dst_s[EB];
    __shared__ float fc_s[EB];

    const int t = threadIdx.x;
    const int base = blockIdx.x * EB;

    // ---- stage meta ----
    if (t < EB) {
        int pos = base + t;
        int e = edge_order[pos];
        e_s[t]   = e;
        src_s[t] = edge_src[pos];
        dst_s[t] = eidx[N_EDGES + e];
        fc_s[t]  = fcut[e];
    }
    // ---- stage rbf A-fragments (independent of e_s: read edge_order directly) ----
    // A-frag: lane l holds row (l&15) [edge], k = (l>>4)*8 + j
    if (t < 128) {
        const int m = t >> 6, l = t & 63;
        const int erow = m * 16 + (l & 15);
        const int e = edge_order[base + erow];
        const int kb = (l >> 4) * 8;
        const float* rrow = rbf + (size_t)e * NUM_BASIS;
        #pragma unroll
        for (int j = 0; j < 8; ++j) {
            const int k = kb + j;
            rbfA[m][l][j] = (k < NUM_BASIS) ? f2bf(rrow[k]) : (unsigned short)0;
        }
    }
    __syncthreads();

    // ---- phase A: GEMM + epilogue ----
    {
        const int w = t >> 6, lane = t & 63;
        const short8v a0 = *(const short8v*)&rbfA[0][lane][0];
        const short8v a1 = *(const short8v*)&rbfA[1][lane][0];
        const int rbase = (lane >> 4) * 4;
        int   dA[4], dB[4];
        float fA[4], fB[4];
        #pragma unroll
        for (int r = 0; r < 4; ++r) {
            dA[r] = dst_s[rbase + r];      fA[r] = fc_s[rbase + r];
            dB[r] = dst_s[16 + rbase + r]; fB[r] = fc_s[16 + rbase + r];
        }
        #pragma unroll
        for (int i = 0; i < NT / 4; ++i) {            // 9 N-tiles per wave
            const int nt = w * (NT / 4) + i;
            const short8v bf = *(const short8v*)(bfrag + (size_t)(nt * 64 + lane) * 8);
            f32x4 c0 = {0.f, 0.f, 0.f, 0.f};
            f32x4 c1 = {0.f, 0.f, 0.f, 0.f};
            c0 = __builtin_amdgcn_mfma_f32_16x16x32_bf16(a0, bf, c0, 0, 0, 0);
            c1 = __builtin_amdgcn_mfma_f32_16x16x32_bf16(a1, bf, c1, 0, 0, 0);
            const int col = nt * 16 + (lane & 15);
            const float brc = br[col];
            #pragma unroll
            for (int r = 0; r < 4; ++r) {
                const int row = rbase + r;
                float v0 = (c0[r] + brc) * fA[r] * so[(size_t)dA[r] * HIDDEN + col];
                float v1 = (c1[r] + brc) * fB[r] * so[(size_t)dB[r] * HIDDEN + col];
                fo_bf[row][col]      = f2bf(v0);
                fo_bf[16 + row][col] = f2bf(v1);
            }
        }
    }
    __syncthreads();

    // ---- phase B: consume, segmented accumulate ----
    const int g1i = (t < 128) ? t : (128 + (t - 128) / 3);
    const int g2i = (t < 64) ? (128 + (128 + t) / 3) : (192 + (t - 64) / 5);

    float accS = 0.f, accD1 = 0.f, accD2 = 0.f;
    int cur_src = src_s[0];

    #pragma unroll 4
    for (int le = 0; le < EB; ++le) {
        const int s = src_s[le];
        if (s != cur_src) {   // block-uniform branch
            atomicAdd(&out_sph[(size_t)cur_src * SPH_DIM + t], accD1);
            if (t < 224) atomicAdd(&out_sph[(size_t)cur_src * SPH_DIM + 256 + t], accD2);
            if (t < 128) atomicAdd(&out_scalar[(size_t)cur_src * NODE_DIM + t], accS);
            accD1 = accD2 = accS = 0.f;
            cur_src = s;
        }
        const int dst = dst_s[le];
        const int eg  = e_s[le];
        const float xv1 = xsp[(size_t)dst * SPH_DIM + t];
        const float rv1 = rsh[(size_t)eg  * SPH_DIM + t];
        accD1 = fmaf(xv1, bf2f(fo_bf[le][g1i]),
                fmaf(rv1, bf2f(fo_bf[le][NUM_IRREPS + g1i]), accD1));
        if (t < 224) {
            const float xv2 = xsp[(size_t)dst * SPH_DIM + 256 + t];
            const float rv2 = rsh[(size_t)eg  * SPH_DIM + 256 + t];
            accD2 = fmaf(xv2, bf2f(fo_bf[le][g2i]),
                    fmaf(rv2, bf2f(fo_bf[le][NUM_IRREPS + g2i]), accD2));
        }
        if (t < 128) accS += bf2f(fo_bf[le][2 * NUM_IRREPS + t]);
    }
    atomicAdd(&out_sph[(size_t)cur_src * SPH_DIM + t], accD1);
    if (t < 224) atomicAdd(&out_sph[(size_t)cur_src * SPH_DIM + 256 + t], accD2);
    if (t < 128) atomicAdd(&out_scalar[(size_t)cur_src * NODE_DIM + t], accS);
}

extern "C" void kernel_launch(void* const* d_in, const int* in_sizes, int n_in,
                              void* d_out, int out_size, void* d_ws, size_t ws_size,
                              hipStream_t stream) {
    const float* x_scalar    = (const float*)d_in[0];
    const float* x_spherical = (const float*)d_in[1];
    const float* rbf         = (const float*)d_in[2];
    const float* fcut        = (const float*)d_in[3];
    const float* rsh         = (const float*)d_in[4];
    const int*   eidx        = (const int*)d_in[5];
    const float* W1          = (const float*)d_in[6];
    const float* b1          = (const float*)d_in[7];
    const float* W2          = (const float*)d_in[8];
    const float* b2          = (const float*)d_in[9];
    const float* Wr          = (const float*)d_in[10];
    const float* br          = (const float*)d_in[11];

    float* out        = (float*)d_out;
    float* out_scalar = out;                                   // (N_NODES, 128)
    float* out_sph    = out + (size_t)N_NODES * NODE_DIM;      // (N_NODES, 480)

    // workspace layout
    float* scalar_out = (float*)d_ws;                          // 10000*576 floats
    int*   counts     = (int*)(scalar_out + (size_t)N_NODES * HIDDEN);   // 10000
    int*   offsets    = counts + N_NODES;                      // 10001
    int*   cursor     = offsets + N_NODES + 1;                 // 10000
    int*   edge_order = cursor + N_NODES;                      // 160000
    int*   edge_src   = edge_order + N_EDGES;                  // 160000
    unsigned short* bfrag = (unsigned short*)((((uintptr_t)(edge_src + N_EDGES)) + 15) & ~(uintptr_t)15);  // 36*64*8 bf16

    init_out<<<2048, 256, 0, stream>>>(x_scalar, x_spherical, out, counts);
    bfrag_prep<<<1, 256, 0, stream>>>(Wr, bfrag);
    hist_kernel<<<(N_EDGES + 255) / 256, 256, 0, stream>>>(eidx, counts);
    scan_kernel<<<1, 1024, 0, stream>>>(counts, offsets, cursor);
    scatter_kernel<<<(N_EDGES + 255) / 256, 256, 0, stream>>>(eidx, cursor, edge_order, edge_src);
    node_mlp<<<(N_NODES + NPB - 1) / NPB, 128, 0, stream>>>(x_scalar, W1, b1, W2, b2, scalar_out);
    edge_mfma<<<N_EDGES / EB, 256, 0, stream>>>(x_spherical, rbf, fcut, rsh, eidx,
                                                bfrag, br, scalar_out, edge_order, edge_src,
                                                out_scalar, out_sph);
}

// Round 10
// 319.517 us; speedup vs baseline: 1.5126x; 1.1179x over previous
//
#include <hip/hip_runtime.h>

#define NODE_DIM 128
#define NUM_IRREPS 224
#define SPH_DIM 480
#define HIDDEN 576   // NODE_DIM + 2*NUM_IRREPS
#define NUM_BASIS 20
#define N_NODES 10000
#define N_EDGES 160000
#define NPB 4        // nodes per block in node MLP
#define EB 16        // edges per window (block)
#define NT 36        // N-tiles (576/16)
#define IRP (NUM_IRREPS + 8)   // padded pair row (words)

typedef __attribute__((ext_vector_type(8))) short short8v;   // 8 bf16
typedef __attribute__((ext_vector_type(4))) float f32x4;

__device__ __forceinline__ unsigned short f2bf(float f) {
    unsigned int u = __builtin_bit_cast(unsigned int, f);
    u = (u + 0x7fff + ((u >> 16) & 1)) >> 16;   // RNE
    return (unsigned short)u;
}
__device__ __forceinline__ float bf2f(unsigned short h) {
    unsigned int u = ((unsigned int)h) << 16;
    return __builtin_bit_cast(float, u);
}

// ---------------- init: d_out = concat(x_scalar, x_spherical); zero counts ----------------
__global__ void init_out(const float* __restrict__ xs,
                         const float* __restrict__ xsp,
                         float* __restrict__ out,
                         int* __restrict__ counts) {
    const int stride = gridDim.x * blockDim.x;
    const int t0 = blockIdx.x * blockDim.x + threadIdx.x;
    for (int i = t0; i < N_NODES * NODE_DIM; i += stride) out[i] = xs[i];
    float* o2 = out + (size_t)N_NODES * NODE_DIM;
    for (int i = t0; i < N_NODES * SPH_DIM; i += stride) o2[i] = xsp[i];
    for (int i = t0; i < N_NODES; i += stride) counts[i] = 0;
}

// ---------------- hist + (last block) Wr->B-fragment prep ----------------
// B-frag for 16x16x32: lane l holds col (l&15), k = (l>>4)*8 + j, j=0..7
__global__ __launch_bounds__(256) void hist_kernel(const int* __restrict__ eidx,
                                                   int* __restrict__ counts,
                                                   const float* __restrict__ Wr,
                                                   unsigned short* __restrict__ bfrag) {
    if (blockIdx.x == gridDim.x - 1) {
        for (int idx = threadIdx.x; idx < NT * 64; idx += 256) {
            const int nt = idx >> 6, l = idx & 63;
            const int col = nt * 16 + (l & 15);
            const int kb = (l >> 4) * 8;
            #pragma unroll
            for (int j = 0; j < 8; ++j) {
                const int k = kb + j;
                bfrag[(size_t)idx * 8 + j] = (k < NUM_BASIS) ? f2bf(Wr[k * HIDDEN + col]) : (unsigned short)0;
            }
        }
        return;
    }
    int i = blockIdx.x * blockDim.x + threadIdx.x;
    if (i < N_EDGES) atomicAdd(&counts[eidx[i]], 1);   // bucket by src
}

// ---------------- node MLP: scalar_out = silu(x@W1+b1)@W2+b2 ----------------
__global__ __launch_bounds__(128) void node_mlp(
    const float* __restrict__ x,
    const float* __restrict__ W1, const float* __restrict__ b1,
    const float* __restrict__ W2, const float* __restrict__ b2,
    float* __restrict__ so) {
    __shared__ float xs[NPB][NODE_DIM];
    __shared__ float hs[NPB][NODE_DIM];
    const int tid = threadIdx.x;
    const int n0 = blockIdx.x * NPB;

    #pragma unroll
    for (int n = 0; n < NPB; ++n) {
        int node = n0 + n;
        xs[n][tid] = (node < N_NODES) ? x[(size_t)node * NODE_DIM + tid] : 0.f;
    }
    __syncthreads();

    float acc[NPB];
    #pragma unroll
    for (int n = 0; n < NPB; ++n) acc[n] = b1[tid];
    for (int k = 0; k < NODE_DIM; ++k) {
        float w = W1[k * NODE_DIM + tid];
        #pragma unroll
        for (int n = 0; n < NPB; ++n) acc[n] = fmaf(xs[n][k], w, acc[n]);
    }
    #pragma unroll
    for (int n = 0; n < NPB; ++n) {
        float v = acc[n];
        hs[n][tid] = v / (1.f + __expf(-v));
    }
    __syncthreads();

    for (int j = tid; j < HIDDEN; j += 128) {
        float a2[NPB];
        #pragma unroll
        for (int n = 0; n < NPB; ++n) a2[n] = b2[j];
        for (int k = 0; k < NODE_DIM; ++k) {
            float w = W2[k * HIDDEN + j];
            #pragma unroll
            for (int n = 0; n < NPB; ++n) a2[n] = fmaf(hs[n][k], w, a2[n]);
        }
        #pragma unroll
        for (int n = 0; n < NPB; ++n) {
            int node = n0 + n;
            if (node < N_NODES) so[(size_t)node * HIDDEN + j] = a2[n];
        }
    }
}

// ---------------- CSR scan / scatter ----------------
__global__ __launch_bounds__(1024) void scan_kernel(const int* __restrict__ counts,
                                                    int* __restrict__ offsets,
                                                    int* __restrict__ cursor) {
    __shared__ int wsum[16];
    const int tid = threadIdx.x;
    int vals[10];
    int run = 0;
    #pragma unroll
    for (int i = 0; i < 10; ++i) {
        int idx = tid * 10 + i;
        int c = (idx < N_NODES) ? counts[idx] : 0;
        vals[i] = run;
        run += c;
    }
    const int lane = tid & 63, w = tid >> 6;
    int inc = run;
    #pragma unroll
    for (int off = 1; off < 64; off <<= 1) {
        int v = __shfl_up(inc, off);
        if (lane >= off) inc += v;
    }
    if (lane == 63) wsum[w] = inc;
    __syncthreads();
    if (w == 0) {
        int v = (lane < 16) ? wsum[lane] : 0;
        #pragma unroll
        for (int off = 1; off < 16; off <<= 1) {
            int u = __shfl_up(v, off);
            if (lane >= off) v += u;
        }
        if (lane < 16) wsum[lane] = v;
    }
    __syncthreads();
    const int wbase = (w > 0) ? wsum[w - 1] : 0;
    const int base = wbase + inc - run;   // exclusive prefix
    #pragma unroll
    for (int i = 0; i < 10; ++i) {
        int idx = tid * 10 + i;
        if (idx < N_NODES) {
            int v = base + vals[i];
            offsets[idx] = v;
            cursor[idx] = v;
        }
    }
    if (tid == 1023) offsets[N_NODES] = wbase + inc;
}

__global__ __launch_bounds__(256) void scatter_kernel(const int* __restrict__ eidx,
                                                      int* __restrict__ cursor,
                                                      int* __restrict__ edge_order,
                                                      int* __restrict__ edge_src) {
    int i = blockIdx.x * blockDim.x + threadIdx.x;
    if (i < N_EDGES) {
        int s = eidx[i];
        int pos = atomicAdd(&cursor[s], 1);
        edge_order[pos] = i;
        edge_src[pos] = s;
    }
}

// ---------------- edge MFMA kernel: 16 sorted edges/block, 8 blocks/CU ----------------
// Phase A: filter GEMM on matrix cores (A = rbf 16x32 bf16 direct from global,
//   B = prepacked Wr frags). Epilogue: fo = (acc+br)*fcut*so[dst] -> paired bf16
//   LDS: pair_s[le][g] = {fo[g] | fo[224+g]<<16}, scal_s[le][t] = fo[448+t].
// Phase B: thread t owns sph d=t, d=256+t (t<224), scalar t (t<128); coalesced
//   xsp/rsh; segmented accumulate, atomicAdd flush on (block-uniform) src change.
__global__ __launch_bounds__(256, 8) void edge_mfma(
    const float* __restrict__ xsp,
    const float* __restrict__ rbf, const float* __restrict__ fcut,
    const float* __restrict__ rsh, const int* __restrict__ eidx,
    const unsigned short* __restrict__ bfrag, const float* __restrict__ br,
    const float* __restrict__ so,
    const int* __restrict__ edge_order, const int* __restrict__ edge_src,
    float* __restrict__ out_scalar, float* __restrict__ out_sph)
{
    __shared__ unsigned int   pair_s[EB][IRP];            // 14.8 KB
    __shared__ unsigned short scal_s[EB][NODE_DIM + 8];   // 4.25 KB
    __shared__ int   e_s[EB];
    __shared__ int   src_s[EB];
    __shared__ int   dst_s[EB];
    __shared__ float fc_s[EB];

    const int t = threadIdx.x;
    const int base = blockIdx.x * EB;
    const int lane = t & 63, w = t >> 6;

    // ---- A-fragment: direct global load (lane l: edge row l&15, k=(l>>4)*8+j) ----
    const int m_row = lane & 15;
    const int kb = (lane >> 4) * 8;
    const int e_row = edge_order[base + m_row];
    short8v a0;
    {
        const float* rrow = rbf + (size_t)e_row * NUM_BASIS;
        #pragma unroll
        for (int j = 0; j < 8; ++j) {
            const int k = kb + j;
            a0[j] = (k < NUM_BASIS) ? (short)f2bf(rrow[k]) : (short)0;
        }
    }

    // ---- stage meta ----
    if (t < EB) {
        int pos = base + t;
        int e = edge_order[pos];
        e_s[t]   = e;
        src_s[t] = edge_src[pos];
        dst_s[t] = eidx[N_EDGES + e];
        fc_s[t]  = fcut[e];
    }
    __syncthreads();

    // ---- phase A: 9 N-tiles per wave ----
    {
        const int rbase = (lane >> 4) * 4;
        int   dA[4];
        float fA[4];
        #pragma unroll
        for (int r = 0; r < 4; ++r) { dA[r] = dst_s[rbase + r]; fA[r] = fc_s[rbase + r]; }
        #pragma unroll
        for (int i = 0; i < NT / 4; ++i) {
            const int nt = w * (NT / 4) + i;
            const short8v bf = *(const short8v*)(bfrag + (size_t)(nt * 64 + lane) * 8);
            f32x4 c0 = {0.f, 0.f, 0.f, 0.f};
            c0 = __builtin_amdgcn_mfma_f32_16x16x32_bf16(a0, bf, c0, 0, 0, 0);
            const int col = nt * 16 + (lane & 15);
            const float brc = br[col];
            #pragma unroll
            for (int r = 0; r < 4; ++r) {
                const int row = rbase + r;
                const float v = (c0[r] + brc) * fA[r] * so[(size_t)dA[r] * HIDDEN + col];
                const unsigned short hv = f2bf(v);
                if (col < NUM_IRREPS) {
                    ((unsigned short*)&pair_s[row][col])[0] = hv;           // state (lo)
                } else if (col < 2 * NUM_IRREPS) {
                    ((unsigned short*)&pair_s[row][col - NUM_IRREPS])[1] = hv; // edge (hi)
                } else {
                    scal_s[row][col - 2 * NUM_IRREPS] = hv;
                }
            }
        }
    }
    __syncthreads();

    // ---- phase B: consume, segmented accumulate ----
    const int g1i = (t < 128) ? t : (128 + (t - 128) / 3);
    const int g2i = (t < 64) ? (128 + (128 + t) / 3) : (192 + (t - 64) / 5);

    float accS = 0.f, accD1 = 0.f, accD2 = 0.f;
    int cur_src = src_s[0];

    #pragma unroll 4
    for (int le = 0; le < EB; ++le) {
        const int s = src_s[le];
        if (s != cur_src) {   // block-uniform branch
            atomicAdd(&out_sph[(size_t)cur_src * SPH_DIM + t], accD1);
            if (t < 224) atomicAdd(&out_sph[(size_t)cur_src * SPH_DIM + 256 + t], accD2);
            if (t < 128) atomicAdd(&out_scalar[(size_t)cur_src * NODE_DIM + t], accS);
            accD1 = accD2 = accS = 0.f;
            cur_src = s;
        }
        const int dst = dst_s[le];
        const int eg  = e_s[le];
        const float xv1 = xsp[(size_t)dst * SPH_DIM + t];
        const float rv1 = rsh[(size_t)eg  * SPH_DIM + t];
        const unsigned int p1 = pair_s[le][g1i];
        accD1 = fmaf(xv1, bf2f((unsigned short)(p1 & 0xffffu)),
                fmaf(rv1, bf2f((unsigned short)(p1 >> 16)), accD1));
        if (t < 224) {
            const float xv2 = xsp[(size_t)dst * SPH_DIM + 256 + t];
            const float rv2 = rsh[(size_t)eg  * SPH_DIM + 256 + t];
            const unsigned int p2 = pair_s[le][g2i];
            accD2 = fmaf(xv2, bf2f((unsigned short)(p2 & 0xffffu)),
                    fmaf(rv2, bf2f((unsigned short)(p2 >> 16)), accD2));
        }
        if (t < 128) accS += bf2f(scal_s[le][t]);
    }
    atomicAdd(&out_sph[(size_t)cur_src * SPH_DIM + t], accD1);
    if (t < 224) atomicAdd(&out_sph[(size_t)cur_src * SPH_DIM + 256 + t], accD2);
    if (t < 128) atomicAdd(&out_scalar[(size_t)cur_src * NODE_DIM + t], accS);
}

extern "C" void kernel_launch(void* const* d_in, const int* in_sizes, int n_in,
                              void* d_out, int out_size, void* d_ws, size_t ws_size,
                              hipStream_t stream) {
    const float* x_scalar    = (const float*)d_in[0];
    const float* x_spherical = (const float*)d_in[1];
    const float* rbf         = (const float*)d_in[2];
    const float* fcut        = (const float*)d_in[3];
    const float* rsh         = (const float*)d_in[4];
    const int*   eidx        = (const int*)d_in[5];
    const float* W1          = (const float*)d_in[6];
    const float* b1          = (const float*)d_in[7];
    const float* W2          = (const float*)d_in[8];
    const float* b2          = (const float*)d_in[9];
    const float* Wr          = (const float*)d_in[10];
    const float* br          = (const float*)d_in[11];

    float* out        = (float*)d_out;
    float* out_scalar = out;                                   // (N_NODES, 128)
    float* out_sph    = out + (size_t)N_NODES * NODE_DIM;      // (N_NODES, 480)

    // workspace layout
    float* scalar_out = (float*)d_ws;                          // 10000*576 floats
    int*   counts     = (int*)(scalar_out + (size_t)N_NODES * HIDDEN);   // 10000
    int*   offsets    = counts + N_NODES;                      // 10001
    int*   cursor     = offsets + N_NODES + 1;                 // 10000
    int*   edge_order = cursor + N_NODES;                      // 160000
    int*   edge_src   = edge_order + N_EDGES;                  // 160000
    unsigned short* bfrag = (unsigned short*)((((uintptr_t)(edge_src + N_EDGES)) + 15) & ~(uintptr_t)15);  // 36*64*8 bf16

    init_out<<<2048, 256, 0, stream>>>(x_scalar, x_spherical, out, counts);
    hist_kernel<<<N_EDGES / 256 + 1, 256, 0, stream>>>(eidx, counts, Wr, bfrag);
    scan_kernel<<<1, 1024, 0, stream>>>(counts, offsets, cursor);
    scatter_kernel<<<(N_EDGES + 255) / 256, 256, 0, stream>>>(eidx, cursor, edge_order, edge_src);
    node_mlp<<<(N_NODES + NPB - 1) / NPB, 128, 0, stream>>>(x_scalar, W1, b1, W2, b2, scalar_out);
    edge_mfma<<<N_EDGES / EB, 256, 0, stream>>>(x_spherical, rbf, fcut, rsh, eidx,
                                                bfrag, br, scalar_out, edge_order, edge_src,
                                                out_scalar, out_sph);
}